// Round 17
// baseline (320.498 us; speedup 1.0000x reference)
//
#include <hip/hip_runtime.h>
#include <math.h>

#define NN 50000
#define EE 800000
#define HH 64
#define GG 512
#define SCAN_NB ((NN + 1023) / 1024)       // 49 blocks (covers NN+1 entries)
#define NC 8                               // privatized deg copies (XCD count)

typedef unsigned short ushort_t;
typedef unsigned int uint_t;

__device__ __forceinline__ ushort_t f32_to_bf16(float f) {
    uint_t u = __float_as_uint(f);
    uint_t bias = 0x7FFFu + ((u >> 16) & 1u);    // round-to-nearest-even
    return (ushort_t)((u + bias) >> 16);
}
__device__ __forceinline__ float bf16_to_f32(ushort_t h) {
    return __uint_as_float(((uint_t)h) << 16);
}

// ---------------- degree (8 XCD-privatized copies) + per-edge local rank ----------------
// copy c = (e>>8)&7: all edges of one 256-thread block hit the same copy; with
// round-robin block->XCD dispatch the atomic stays in the local XCD L2.

__global__ void k_deg(const int* __restrict__ dst, int* __restrict__ degc,
                      int* __restrict__ rank) {
    int e = blockIdx.x * blockDim.x + threadIdx.x;
    if (e < EE) {
        int c = (e >> 8) & (NC - 1);
        rank[e] = atomicAdd(&degc[c * NN + dst[e]], 1);
    }
}

// ---------------- scan: total deg -> block-local rowptr + bsum; per-copy offsets ----------

__global__ void __launch_bounds__(1024) k_scan1(const int* __restrict__ degc,
                                                int* __restrict__ rowptr,
                                                int* __restrict__ bsum,
                                                uint4* __restrict__ off8,
                                                float* __restrict__ dinv) {
    int tid = threadIdx.x;
    int lane = tid & 63, w = tid >> 6;
    int i = blockIdx.x * 1024 + tid;
    int total = 0;
    int offv[NC];
#pragma unroll
    for (int c = 0; c < NC; ++c) {
        int dc = (i < NN) ? degc[c * NN + i] : 0;
        offv[c] = total;
        total += dc;
    }
    if (i < NN) {
        dinv[i] = 1.0f / sqrtf((float)(total + 1));   // +1 self-loop
        off8[i] = make_uint4((uint_t)offv[0] | ((uint_t)offv[1] << 16),
                             (uint_t)offv[2] | ((uint_t)offv[3] << 16),
                             (uint_t)offv[4] | ((uint_t)offv[5] << 16),
                             (uint_t)offv[6] | ((uint_t)offv[7] << 16));
    } else if (i == NN) {
        dinv[i] = 0.0f;                               // zero row
    }
    int v = (i < NN) ? total : 0;
    int x = v;                                        // inclusive wave scan
#pragma unroll
    for (int off = 1; off < 64; off <<= 1) {
        int y = __shfl_up(x, off);
        if (lane >= off) x += y;
    }
    __shared__ int ws[16];
    if (lane == 63) ws[w] = x;
    __syncthreads();
    if (tid < 16) {
        int y = ws[tid];
        int z = y;
#pragma unroll
        for (int off = 1; off < 16; off <<= 1) {
            int t2 = __shfl_up(z, off);
            if (tid >= off) z += t2;
        }
        ws[tid] = z - y;                          // exclusive wave offsets
    }
    __syncthreads();
    int excl = x - v + ws[w];
    if (i <= NN) rowptr[i] = excl;                // block-local exclusive prefix
    if (tid == 1023) bsum[blockIdx.x] = excl + v; // block total
}

__global__ void __launch_bounds__(64) k_scan2(int* __restrict__ bsum) {
    int lane = threadIdx.x;
    int v = (lane < SCAN_NB) ? bsum[lane] : 0;
    int x = v;
#pragma unroll
    for (int off = 1; off < 64; off <<= 1) {
        int y = __shfl_up(x, off);
        if (lane >= off) x += y;
    }
    if (lane < SCAN_NB) bsum[lane] = x - v;       // exclusive block offsets
}

// ---------------- absolute bases: rowptr_abs + per-copy base8 ----------------

__global__ void k_base(const int* __restrict__ rowptr, const int* __restrict__ bsum,
                       const uint4* __restrict__ off8,
                       int* __restrict__ rowptr_abs, int* __restrict__ base8) {
    int i = blockIdx.x * blockDim.x + threadIdx.x;
    if (i > NN) return;
    int base = rowptr[i] + bsum[i >> 10];
    rowptr_abs[i] = base;
    if (i < NN) {
        uint4 pk = off8[i];
        base8[0 * NN + i] = base + (int)(pk.x & 0xFFFFu);
        base8[1 * NN + i] = base + (int)(pk.x >> 16);
        base8[2 * NN + i] = base + (int)(pk.y & 0xFFFFu);
        base8[3 * NN + i] = base + (int)(pk.y >> 16);
        base8[4 * NN + i] = base + (int)(pk.z & 0xFFFFu);
        base8[5 * NN + i] = base + (int)(pk.z >> 16);
        base8[6 * NN + i] = base + (int)(pk.w & 0xFFFFu);
        base8[7 * NN + i] = base + (int)(pk.w >> 16);
    }
}

// ---------------- CSR fill: atomic-free u16 edge scatter + per-graph counts ----------------

__global__ void k_fill(const int* __restrict__ src, const int* __restrict__ dst,
                       const int* __restrict__ rank, const int* __restrict__ base8,
                       const int* __restrict__ batch,
                       ushort_t* __restrict__ csr_src, int* __restrict__ cnt) {
    int tid = blockIdx.x * blockDim.x + threadIdx.x;
    if (tid < EE) {
        int d = dst[tid];
        int c = (tid >> 8) & (NC - 1);            // same copy mapping as k_deg
        csr_src[base8[c * NN + d] + rank[tid]] = (ushort_t)src[tid];
    } else if (tid < EE + NN) {
        atomicAdd(&cnt[batch[tid - EE]], 1);
    }
}

// ---------------- dense transform: t' = bf16((act(x) @ W) * dinv[row]); row NN zeroed ------

template<bool RELU>
__global__ void __launch_bounds__(256) k_xform(const float* __restrict__ x,
                                               const float* __restrict__ W,
                                               const float* __restrict__ dinv,
                                               ushort_t* __restrict__ t) {
    __shared__ float sW[64 * 64];   // 16 KB
    __shared__ float sX[32 * 65];   // padded
    int tid = threadIdx.x;
    for (int k = tid; k < 64 * 64; k += 256) sW[k] = W[k];
    int row0 = blockIdx.x * 32;
    for (int v = tid; v < 32 * 16; v += 256) {
        int r  = v >> 4;
        int k4 = (v & 15) * 4;
        int row = row0 + r;
        float4 val = make_float4(0.f, 0.f, 0.f, 0.f);
        if (row < NN) val = *(const float4*)(x + (size_t)row * 64 + k4);
        if (RELU) {
            val.x = fmaxf(val.x, 0.f); val.y = fmaxf(val.y, 0.f);
            val.z = fmaxf(val.z, 0.f); val.w = fmaxf(val.w, 0.f);
        }
        sX[r * 65 + k4 + 0] = val.x;
        sX[r * 65 + k4 + 1] = val.y;
        sX[r * 65 + k4 + 2] = val.z;
        sX[r * 65 + k4 + 3] = val.w;
    }
    __syncthreads();
    int r  = tid >> 3;        // 0..31
    int c0 = (tid & 7) * 8;   // 0,8,...,56
    float acc[8] = {0.f, 0.f, 0.f, 0.f, 0.f, 0.f, 0.f, 0.f};
    for (int k = 0; k < 64; ++k) {
        float xv = sX[r * 65 + k];
#pragma unroll
        for (int j = 0; j < 8; ++j) acc[j] = fmaf(xv, sW[k * 64 + c0 + j], acc[j]);
    }
    int row = row0 + r;
    if (row <= NN) {          // row NN: acc==0 -> writes zero row
        float dv = dinv[row];
        uint_t pk[4];
#pragma unroll
        for (int j = 0; j < 4; ++j) {
            ushort_t lo = f32_to_bf16(acc[2 * j] * dv);
            ushort_t hi = f32_to_bf16(acc[2 * j + 1] * dv);
            pk[j] = (uint_t)lo | ((uint_t)hi << 16);
        }
        uint4* o = (uint4*)(t + (size_t)row * 64 + c0);   // 16 B per lane
        *o = make_uint4(pk[0], pk[1], pk[2], pk[3]);
    }
}

// ---------------- CSR gather: one wave per node, 16-deep batches, bf16 rows, u16 idx -------
// out[i] = dinv[i] * (t'[i] + sum_{s in N(i)} t'[s]) + b

template<bool POOL>
__global__ void __launch_bounds__(256) k_gather(const ushort_t* __restrict__ t,
                                                const float* __restrict__ dinv,
                                                const int* __restrict__ rowptr_abs,
                                                const ushort_t* __restrict__ csr_src,
                                                const float* __restrict__ b,
                                                const int* __restrict__ batch,
                                                float* __restrict__ out) {
    int i = __builtin_amdgcn_readfirstlane((blockIdx.x * blockDim.x + threadIdx.x) >> 6);
    int c = threadIdx.x & 63;
    if (i >= NN) return;
    int e   = __builtin_amdgcn_readfirstlane(rowptr_abs[i]);
    int end = __builtin_amdgcn_readfirstlane(rowptr_abs[i + 1]);
    float acc = bf16_to_f32(t[(size_t)i * 64 + c]);   // self-loop (t' already *dinv[i])
    float a0 = 0.f, a1 = 0.f, a2 = 0.f, a3 = 0.f;
    for (; e < end; e += 16) {                    // 16 outstanding row-gathers
        int s[16];
#pragma unroll
        for (int j = 0; j < 16; ++j) {
            int sj = (int)csr_src[e + j];         // uniform addr -> scalar-load, broadcast
            s[j] = (e + j < end) ? sj : NN;       // uniform select; NN = zero row
        }
        ushort_t v[16];
#pragma unroll
        for (int j = 0; j < 16; ++j) v[j] = t[(size_t)s[j] * 64 + c];
#pragma unroll
        for (int j = 0; j < 16; ++j) {
            float f = bf16_to_f32(v[j]);
            if ((j & 3) == 0)      a0 += f;
            else if ((j & 3) == 1) a1 += f;
            else if ((j & 3) == 2) a2 += f;
            else                   a3 += f;
        }
    }
    acc += (a0 + a1) + (a2 + a3);
    float r = fmaf(acc, dinv[i], b[c]);
    if (POOL) {
        atomicAdd(&out[(size_t)batch[i] * 64 + c], fmaxf(r, 0.0f));
    } else {
        out[(size_t)i * 64 + c] = r;
    }
}

// ---------------- head: per-graph MLP, one wave per graph ----------------

__global__ void __launch_bounds__(64) k_head(const float* __restrict__ pooled,
                                             const int* __restrict__ cnt,
                                             const float* __restrict__ w1,
                                             const float* __restrict__ b1,
                                             const float* __restrict__ w2,
                                             const float* __restrict__ b2,
                                             float* __restrict__ out) {
    int g = blockIdx.x;
    int c = threadIdx.x;
    __shared__ float sp[64];
    float cf = fmaxf((float)cnt[g], 1.0f);
    sp[c] = pooled[(size_t)g * 64 + c] / cf;
    __syncthreads();
    float acc = b1[c];
    for (int k = 0; k < 64; ++k) acc = fmaf(sp[k], w1[k * 64 + c], acc);
    float h1 = fmaxf(acc, 0.0f);
    float p = h1 * w2[c];
#pragma unroll
    for (int off = 32; off > 0; off >>= 1) p += __shfl_down(p, off);
    if (c == 0) out[g] = p + b2[0];
}

// ---------------- launch ----------------

extern "C" void kernel_launch(void* const* d_in, const int* in_sizes, int n_in,
                              void* d_out, int out_size, void* d_ws, size_t ws_size,
                              hipStream_t stream) {
    const float* x      = (const float*)d_in[0];
    const int*   ei     = (const int*)d_in[1];
    const int*   batch  = (const int*)d_in[2];
    const float* W0     = (const float*)d_in[3];
    const float* b0     = (const float*)d_in[4];
    const float* W1     = (const float*)d_in[5];
    const float* b1     = (const float*)d_in[6];
    const float* W2     = (const float*)d_in[7];
    const float* b2     = (const float*)d_in[8];
    const float* lin1w  = (const float*)d_in[9];
    const float* lin1b  = (const float*)d_in[10];
    const float* lin2w  = (const float*)d_in[11];
    const float* lin2b  = (const float*)d_in[12];
    float* out = (float*)d_out;

    const int* src = ei;
    const int* dst = ei + EE;

    char* ws = (char*)d_ws;
    size_t off = 0;
    auto carve = [&](size_t bytes) {
        void* p = ws + off;
        off = (off + bytes + 255) & ~(size_t)255;
        return p;
    };
    // zero-initialized group first (single memset covers [0, zero_span))
    int*      degc     = (int*)carve((size_t)NC * NN * 4);       // 8 privatized copies
    float*    pooled   = (float*)carve((size_t)GG * 64 * 4);
    int*      cnt      = (int*)carve((size_t)GG * 4);
    size_t zero_span = off;
    float*    dinv     = (float*)carve((size_t)(NN + 1) * 4);
    int*      rowptr   = (int*)carve((size_t)(NN + 1) * 4);
    int*      bsum     = (int*)carve((size_t)SCAN_NB * 4);
    uint4*    off8     = (uint4*)carve((size_t)NN * 16);
    int*      rowptr_abs = (int*)carve((size_t)(NN + 1) * 4);
    int*      base8    = (int*)carve((size_t)NC * NN * 4);
    int*      rank     = (int*)carve((size_t)EE * 4);
    ushort_t* csr_src  = (ushort_t*)carve((size_t)(EE + 16) * 2); // +16 masked overrun
    ushort_t* bufT     = (ushort_t*)carve((size_t)(NN + 1) * 64 * 2);  // bf16, +1 zero row
    float*    bufA     = (float*)carve((size_t)NN * 64 * 4);

    hipMemsetAsync(degc, 0, zero_span, stream);

    // ---- CSR build (privatized counters; rank-based atomic-free u16 fill) ----
    k_deg  <<<EE / 256, 256, 0, stream>>>(dst, degc, rank);
    k_scan1<<<SCAN_NB, 1024, 0, stream>>>(degc, rowptr, bsum, off8, dinv);
    k_scan2<<<1, 64, 0, stream>>>(bsum);
    k_base <<<(NN + 256) / 256, 256, 0, stream>>>(rowptr, bsum, off8, rowptr_abs, base8);
    k_fill <<<(EE + NN + 255) / 256, 256, 0, stream>>>(src, dst, rank, base8,
                                                       batch, csr_src, cnt);

    const int xgrid = (NN + 1 + 31) / 32;        // includes zero row NN
    const int ggrid = (NN * 64) / 256;           // one 64-lane wave per node

    // layer 0: x -> bufA
    k_xform<false><<<xgrid, 256, 0, stream>>>(x, W0, dinv, bufT);
    k_gather<false><<<ggrid, 256, 0, stream>>>(bufT, dinv, rowptr_abs, csr_src,
                                               b0, batch, bufA);
    // layer 1
    k_xform<true><<<xgrid, 256, 0, stream>>>(bufA, W1, dinv, bufT);
    k_gather<false><<<ggrid, 256, 0, stream>>>(bufT, dinv, rowptr_abs, csr_src,
                                               b1, batch, bufA);
    // layer 2: relu + mean-pool fused into gather
    k_xform<true><<<xgrid, 256, 0, stream>>>(bufA, W2, dinv, bufT);
    k_gather<true><<<ggrid, 256, 0, stream>>>(bufT, dinv, rowptr_abs, csr_src,
                                              b2, batch, pooled);

    k_head<<<GG, 64, 0, stream>>>(pooled, cnt, lin1w, lin1b, lin2w, lin2b, out);
}